// Round 1
// baseline (611.012 us; speedup 1.0000x reference)
//
#include <hip/hip_runtime.h>

typedef _Float16 hh;
typedef _Float16 h2 __attribute__((ext_vector_type(2)));

#define T_STEPS 36
#define FEAT 9
#define HID 64
#define NGATE 256     // 4*HID
#define BT 32         // batch elements per block
#define WG_STR 43     // half2 stride of a gate-weight row (86 halves; 84 used)
#define SIN_STR 44    // half2 stride of an s_in row (88 halves; 16B aligned)

__device__ __forceinline__ float fdot2(h2 a, h2 b, float c) {
#if __has_builtin(__builtin_amdgcn_fdot2)
  return __builtin_amdgcn_fdot2(a, b, c, false);
#else
  return c + (float)a.x * (float)b.x + (float)a.y * (float)b.y;
#endif
}

__device__ __forceinline__ float sigmoid_fast(float x) {
  return 1.f / (1.f + __expf(-x));
}
__device__ __forceinline__ float tanh_fast(float x) {
  x = fminf(20.f, fmaxf(-20.f, x));
  float e = __expf(2.f * x);
  return (e - 1.f) / (e + 1.f);
}

// ---------------- kernel 0: zero ws denom slots + loss slot ----------------
__global__ void zero_ws(float* __restrict__ ws, float* __restrict__ out) {
  int tid = threadIdx.x;
  if (tid < T_STEPS) ws[tid] = 0.f;
  if (tid == 0) out[0] = 0.f;
}

// ---------------- kernel 1: denom[t] = sum over (B,FEAT) of masks[:,t,:] ---
__global__ void denom_kernel(const float* __restrict__ masks, float* __restrict__ ws, int B) {
  __shared__ float red[256];
  int t = blockIdx.x, s = blockIdx.y, tid = threadIdx.x;
  int n = B * FEAT;
  int chunk = (n + 7) / 8;
  int beg = s * chunk;
  int end = beg + chunk; if (end > n) end = n;
  float acc = 0.f;
  for (int i = beg + tid; i < end; i += 256) {
    int e = i / FEAT, f = i - e * FEAT;
    acc += masks[e * (T_STEPS * FEAT) + t * FEAT + f];
  }
  red[tid] = acc;
  __syncthreads();
  for (int k = 128; k > 0; k >>= 1) {
    if (tid < k) red[tid] += red[tid + k];
    __syncthreads();
  }
  if (tid == 0) atomicAdd(&ws[t], red[0]);
}

// ---------------- kernel 2: the full RITS scan -----------------------------
__global__ __launch_bounds__(256) void rits_kernel(
    const float* __restrict__ values, const float* __restrict__ masks,
    const float* __restrict__ deltas,
    const float* __restrict__ W_gh, const float* __restrict__ b_gh,
    const float* __restrict__ W_gx, const float* __restrict__ b_gx,
    const float* __restrict__ W_hist, const float* __restrict__ b_hist,
    const float* __restrict__ W_feat, const float* __restrict__ b_feat,
    const float* __restrict__ W_comb, const float* __restrict__ b_comb,
    const float* __restrict__ W_ih, const float* __restrict__ W_hh,
    const float* __restrict__ b_ih, const float* __restrict__ b_hh,
    const float* __restrict__ denom, float* __restrict__ out) {

  // s_in row (halves): [0..8]=c_c  [9..17]=m  [18..81]=h  [82]=1(bias)  [83..87]=0
  // gate row (halves): [0..17]=W_ih[r]  [18..81]=W_hh[r]  [82]=b_ih[r]+b_hh[r]  [83]=0
  __shared__ h2 sWg[NGATE * WG_STR];                    // 44032 B
  __shared__ __align__(16) h2 sIn[BT * SIN_STR];        //  5632 B
  __shared__ float sX[BT * FEAT];                       //  1152 B
  __shared__ hh    sM[BT * FEAT];                       //   576 B
  __shared__ h2    sD[BT * 5];                          //   640 B (10 halves/row)
  __shared__ float sXH[BT * FEAT];                      //  1152 B
  __shared__ hh    sXC[BT * FEAT];                      //   576 B
  __shared__ hh    sGX[BT * FEAT];                      //   576 B
  __shared__ h2    sWgh[HID * 5];                       //  1280 B (10 halves/row)
  __shared__ float sbgh[HID];
  __shared__ h2    sWhist[FEAT * 32];                   //  1152 B
  __shared__ float sbhist[FEAT];
  __shared__ float sWfeat[FEAT * FEAT];
  __shared__ float sbfeat[FEAT];
  __shared__ float sWcomb[FEAT * 2 * FEAT];
  __shared__ float sbcomb[FEAT];
  __shared__ float sWgxd[FEAT];
  __shared__ float sbgx[FEAT];
  __shared__ float sRed[256];

  const int tid = threadIdx.x;
  const int b0 = blockIdx.x * BT;

  // ---- fill weights / pads / t=0 tiles (one phase, one barrier) ----
  for (int i = tid; i < NGATE * 84; i += 256) {
    int r = i / 84, k = i - r * 84;
    float v;
    if (k < 18) v = W_ih[r * 18 + k];
    else if (k < 82) v = W_hh[r * 64 + (k - 18)];
    else if (k == 82) v = b_ih[r] + b_hh[r];
    else v = 0.f;
    ((hh*)sWg)[r * (WG_STR * 2) + k] = (hh)v;
  }
  for (int i = tid; i < HID * FEAT; i += 256) {
    int j = i / FEAT, f = i - j * FEAT;
    ((hh*)sWgh)[j * 10 + f] = (hh)W_gh[i];
  }
  for (int i = tid; i < FEAT * HID; i += 256)
    ((hh*)sWhist)[i] = (hh)W_hist[i];
  if (tid < HID) { sbgh[tid] = b_gh[tid]; ((hh*)sWgh)[tid * 10 + 9] = (hh)0.f; }
  if (tid < FEAT) {
    sbhist[tid] = b_hist[tid]; sbfeat[tid] = b_feat[tid]; sbcomb[tid] = b_comb[tid];
    sbgx[tid] = b_gx[tid]; sWgxd[tid] = W_gx[tid * FEAT + tid];
  }
  if (tid < FEAT * FEAT) {
    int f = tid / FEAT, f2 = tid - f * FEAT;
    sWfeat[tid] = (f == f2) ? 0.f : W_feat[tid];
  }
  if (tid < FEAT * 2 * FEAT) sWcomb[tid] = W_comb[tid];
  if (tid < BT) {
    ((hh*)sIn)[tid * (SIN_STR * 2) + 82] = (hh)1.f;   // bias one
    ((hh*)sIn)[tid * (SIN_STR * 2) + 83] = (hh)0.f;   // pad
    ((hh*)sD)[tid * 10 + 9] = (hh)0.f;                // d pad
  }
  // stage t = 0 tiles
  for (int i = tid; i < BT * FEAT; i += 256) {
    int e = i / FEAT, f = i - e * FEAT;
    int off = (b0 + e) * (T_STEPS * FEAT) + f;        // t = 0
    sX[i] = values[off];
    sM[i] = (hh)masks[off];
    ((hh*)sD)[e * 10 + f] = (hh)deltas[off];
  }
  __syncthreads();

  // ---- per-thread persistent state ----
  const int j  = tid & 63;        // hidden index (phases A, C)
  const int eg = tid >> 6;        // element-group 0..3
  const int ec0 = eg * 8;         // 8 elements per thread in A/C
  const int eB = tid >> 3;        // element for phase B (0..31)
  const int fqB = tid & 7;        // feature lane for phase B

  float c_st[8], h_prev[8];
#pragma unroll
  for (int e = 0; e < 8; ++e) { c_st[e] = 0.f; h_prev[e] = 0.f; }
  float loss_acc = 0.f;

  const h2* wrI = &sWg[(0 * HID + j) * WG_STR];
  const h2* wrF = &sWg[(1 * HID + j) * WG_STR];
  const h2* wrG = &sWg[(2 * HID + j) * WG_STR];
  const h2* wrO = &sWg[(3 * HID + j) * WG_STR];

  for (int t = 0; t < T_STEPS; ++t) {
    const float inv_den = 1.f / (denom[t] + 1e-5f);

    // ---- Phase A: gamma_h, decay h, publish h (fp16) to s_in ----
#pragma unroll
    for (int e = 0; e < 8; ++e) {
      int ee = ec0 + e;
      float acc = sbgh[j];
      const h2* dr = &sD[ee * 5];
      const h2* wr = &sWgh[j * 5];
#pragma unroll
      for (int q = 0; q < 5; ++q) acc = fdot2(wr[q], dr[q], acc);
      float gam = __expf(-fmaxf(acc, 0.f));
      float hd = h_prev[e] * gam;
      h_prev[e] = hd;
      ((hh*)sIn)[ee * (SIN_STR * 2) + 18 + j] = (hh)hd;
    }
    __syncthreads();

    // ---- Phase B1: x_h (h @ W_hist^T), gamma_x, x_c ----
    for (int f = fqB; f < FEAT; f += 8) {
      float acc = sbhist[f];
      const h2* hr = &sIn[eB * SIN_STR + 9];   // h starts at half 18 = h2 9
      const h2* wr = &sWhist[f * 32];
#pragma unroll
      for (int q = 0; q < 32; ++q) acc = fdot2(hr[q], wr[q], acc);
      sXH[eB * FEAT + f] = acc;
      float d = (float)((const hh*)sD)[eB * 10 + f];
      float gx = __expf(-fmaxf(d * sWgxd[f] + sbgx[f], 0.f));
      sGX[eB * FEAT + f] = (hh)gx;
      float m = (float)sM[eB * FEAT + f];
      sXC[eB * FEAT + f] = (hh)(m * sX[eB * FEAT + f] + (1.f - m) * acc);
    }
    __syncthreads();

    // ---- Phase B2: z_h, alpha, c_h, c_c, loss, imputation store ----
    float step_loss = 0.f;
    for (int f = fqB; f < FEAT; f += 8) {
      float zh = sbfeat[f];
#pragma unroll
      for (int f2 = 0; f2 < FEAT; ++f2)
        zh += (float)sXC[eB * FEAT + f2] * sWfeat[f * FEAT + f2];
      float al = sbcomb[f];
#pragma unroll
      for (int k = 0; k < FEAT; ++k)
        al += (float)sGX[eB * FEAT + k] * sWcomb[f * 18 + k];
#pragma unroll
      for (int k = 0; k < FEAT; ++k)
        al += (float)sM[eB * FEAT + k] * sWcomb[f * 18 + 9 + k];
      float xh = sXH[eB * FEAT + f];
      float ch = al * zh + (1.f - al) * xh;
      float m = (float)sM[eB * FEAT + f];
      float x = sX[eB * FEAT + f];
      float cc = m * x + (1.f - m) * ch;
      step_loss += m * (fabsf(x - xh) + fabsf(x - zh) + fabsf(x - ch));
      ((hh*)sIn)[eB * (SIN_STR * 2) + f] = (hh)cc;
      ((hh*)sIn)[eB * (SIN_STR * 2) + 9 + f] = sM[eB * FEAT + f];
      out[1 + (b0 + eB) * (T_STEPS * FEAT) + t * FEAT + f] = cc;
    }
    loss_acc += step_loss * inv_den;
    __syncthreads();

    // ---- Phase C: gates via fp16 dot2, LSTM pointwise; prefetch t+1 ----
    float px0 = 0, pm0 = 0, pd0 = 0, px1 = 0, pm1 = 0, pd1 = 0;
    if (t + 1 < T_STEPS) {
      int e = tid / FEAT, f = tid - e * FEAT;
      int off = (b0 + e) * (T_STEPS * FEAT) + (t + 1) * FEAT + f;
      px0 = values[off]; pm0 = masks[off]; pd0 = deltas[off];
      if (tid < BT * FEAT - 256) {
        int i1 = tid + 256; int e1 = i1 / FEAT, f1 = i1 - e1 * FEAT;
        int off1 = (b0 + e1) * (T_STEPS * FEAT) + (t + 1) * FEAT + f1;
        px1 = values[off1]; pm1 = masks[off1]; pd1 = deltas[off1];
      }
    }

    float ai[8], af_[8], ag[8], ao[8];
#pragma unroll
    for (int e = 0; e < 8; ++e) { ai[e] = 0.f; af_[e] = 0.f; ag[e] = 0.f; ao[e] = 0.f; }

    for (int kc = 0; kc < 10; ++kc) {
      int kb = kc * 4;
      h2 wI[4], wF[4], wG[4], wO[4];
#pragma unroll
      for (int q = 0; q < 4; ++q) {
        wI[q] = wrI[kb + q]; wF[q] = wrF[kb + q];
        wG[q] = wrG[kb + q]; wO[q] = wrO[kb + q];
      }
#pragma unroll
      for (int e = 0; e < 8; ++e) {
        float4 sv = *reinterpret_cast<const float4*>(&sIn[(ec0 + e) * SIN_STR + kb]);
        h2 s0 = __builtin_bit_cast(h2, sv.x);
        h2 s1 = __builtin_bit_cast(h2, sv.y);
        h2 s2 = __builtin_bit_cast(h2, sv.z);
        h2 s3 = __builtin_bit_cast(h2, sv.w);
        float vi = ai[e], vf = af_[e], vg = ag[e], vo = ao[e];
        vi = fdot2(wI[0], s0, vi); vi = fdot2(wI[1], s1, vi);
        vi = fdot2(wI[2], s2, vi); vi = fdot2(wI[3], s3, vi);
        vf = fdot2(wF[0], s0, vf); vf = fdot2(wF[1], s1, vf);
        vf = fdot2(wF[2], s2, vf); vf = fdot2(wF[3], s3, vf);
        vg = fdot2(wG[0], s0, vg); vg = fdot2(wG[1], s1, vg);
        vg = fdot2(wG[2], s2, vg); vg = fdot2(wG[3], s3, vg);
        vo = fdot2(wO[0], s0, vo); vo = fdot2(wO[1], s1, vo);
        vo = fdot2(wO[2], s2, vo); vo = fdot2(wO[3], s3, vo);
        ai[e] = vi; af_[e] = vf; ag[e] = vg; ao[e] = vo;
      }
    }
    { // tail: half2 40,41 (halves 80..83: h[62], h[63], bias, 0)
      h2 wI0 = wrI[40], wI1 = wrI[41];
      h2 wF0 = wrF[40], wF1 = wrF[41];
      h2 wG0 = wrG[40], wG1 = wrG[41];
      h2 wO0 = wrO[40], wO1 = wrO[41];
#pragma unroll
      for (int e = 0; e < 8; ++e) {
        float2 sv = *reinterpret_cast<const float2*>(&sIn[(ec0 + e) * SIN_STR + 40]);
        h2 s0 = __builtin_bit_cast(h2, sv.x);
        h2 s1 = __builtin_bit_cast(h2, sv.y);
        ai[e]  = fdot2(wI0, s0, fdot2(wI1, s1, ai[e]));
        af_[e] = fdot2(wF0, s0, fdot2(wF1, s1, af_[e]));
        ag[e]  = fdot2(wG0, s0, fdot2(wG1, s1, ag[e]));
        ao[e]  = fdot2(wO0, s0, fdot2(wO1, s1, ao[e]));
      }
    }
#pragma unroll
    for (int e = 0; e < 8; ++e) {
      float ig = sigmoid_fast(ai[e]);
      float fg = sigmoid_fast(af_[e]);
      float gg = tanh_fast(ag[e]);
      float og = sigmoid_fast(ao[e]);
      float cn = fg * c_st[e] + ig * gg;
      c_st[e] = cn;
      h_prev[e] = og * tanh_fast(cn);
    }

    // commit prefetched t+1 tiles (B-phase readers of t are past their barrier)
    if (t + 1 < T_STEPS) {
      int e = tid / FEAT, f = tid - e * FEAT;
      sX[tid] = px0; sM[tid] = (hh)pm0; ((hh*)sD)[e * 10 + f] = (hh)pd0;
      if (tid < BT * FEAT - 256) {
        int i1 = tid + 256; int e1 = i1 / FEAT, f1 = i1 - e1 * FEAT;
        sX[i1] = px1; sM[i1] = (hh)pm1; ((hh*)sD)[e1 * 10 + f1] = (hh)pd1;
      }
    }
    __syncthreads();
  }

  // ---- loss reduction ----
  sRed[tid] = loss_acc;
  __syncthreads();
  for (int k = 128; k > 0; k >>= 1) {
    if (tid < k) sRed[tid] += sRed[tid + k];
    __syncthreads();
  }
  if (tid == 0) atomicAdd(out, sRed[0] * (1.f / (float)T_STEPS));
}

extern "C" void kernel_launch(void* const* d_in, const int* in_sizes, int n_in,
                              void* d_out, int out_size, void* d_ws, size_t ws_size,
                              hipStream_t stream) {
  const float* values = (const float*)d_in[0];
  const float* masks  = (const float*)d_in[1];
  const float* deltas = (const float*)d_in[2];
  const float* W_gh   = (const float*)d_in[3];
  const float* b_gh   = (const float*)d_in[4];
  const float* W_gx   = (const float*)d_in[5];
  const float* b_gx   = (const float*)d_in[6];
  const float* W_hist = (const float*)d_in[7];
  const float* b_hist = (const float*)d_in[8];
  const float* W_feat = (const float*)d_in[9];
  const float* b_feat = (const float*)d_in[10];
  const float* W_comb = (const float*)d_in[11];
  const float* b_comb = (const float*)d_in[12];
  const float* W_ih   = (const float*)d_in[13];
  const float* W_hh   = (const float*)d_in[14];
  const float* b_ih   = (const float*)d_in[15];
  const float* b_hh   = (const float*)d_in[16];

  float* out = (float*)d_out;
  float* ws  = (float*)d_ws;
  int B = in_sizes[0] / (T_STEPS * FEAT);

  zero_ws<<<1, 64, 0, stream>>>(ws, out);
  denom_kernel<<<dim3(T_STEPS, 8), 256, 0, stream>>>(masks, ws, B);
  rits_kernel<<<B / BT, 256, 0, stream>>>(values, masks, deltas,
                                          W_gh, b_gh, W_gx, b_gx,
                                          W_hist, b_hist, W_feat, b_feat,
                                          W_comb, b_comb, W_ih, W_hh,
                                          b_ih, b_hh, ws, out);
}

// Round 2
// 318.731 us; speedup vs baseline: 1.9170x; 1.9170x over previous
//
#include <hip/hip_runtime.h>

typedef _Float16 hh;
typedef _Float16 v8h __attribute__((ext_vector_type(8)));
typedef float v4f __attribute__((ext_vector_type(4)));

#define T_STEPS 36
#define FEAT 9
#define HID 64
#define BT 32          // batch elements per block
#define SIN_STR 104    // halves per sIn row: [c_c 0..8 | m 9..17 | h 18..81 | 1 @82 | 0 @83 | d 84..92 | 0 93..95 | pad]
#define SIN2_STR 32    // halves per sIn2 row: [x_c 0..8 | gx 9..17 | m 18..26 | 1 @27 | 0 28..31]
#define XH_STR 10      // floats
#define X_STR 10       // floats
#define M_STR 10       // halves
#define ZA_STR 20      // floats: z @0..8, alpha @10..18

__device__ __forceinline__ float sigmoid_fast(float x) {
  return 1.f / (1.f + __expf(-x));
}
__device__ __forceinline__ float tanh_fast(float x) {
  x = fminf(20.f, fmaxf(-20.f, x));
  float e = __expf(2.f * x);
  return (e - 1.f) / (e + 1.f);
}
__device__ __forceinline__ v4f mfma16(v8h a, v8h b, v4f c) {
  return __builtin_amdgcn_mfma_f32_16x16x32_f16(a, b, c, 0, 0, 0);
}

// ---------------- kernel 0: zero ws denom slots + loss slot ----------------
__global__ void zero_ws(float* __restrict__ ws, float* __restrict__ out) {
  int tid = threadIdx.x;
  if (tid < T_STEPS) ws[tid] = 0.f;
  if (tid == 0) out[0] = 0.f;
}

// ---------------- kernel 1: denom[t] = sum over (B,FEAT) of masks[:,t,:] ---
__global__ void denom_kernel(const float* __restrict__ masks, float* __restrict__ ws, int B) {
  __shared__ float red[256];
  int t = blockIdx.x, s = blockIdx.y, tid = threadIdx.x;
  int n = B * FEAT;
  int chunk = (n + 31) / 32;
  int beg = s * chunk;
  int end = beg + chunk; if (end > n) end = n;
  float acc = 0.f;
  for (int i = beg + tid; i < end; i += 256) {
    int e = i / FEAT, f = i - e * FEAT;
    acc += masks[e * (T_STEPS * FEAT) + t * FEAT + f];
  }
  red[tid] = acc;
  __syncthreads();
  for (int k = 128; k > 0; k >>= 1) {
    if (tid < k) red[tid] += red[tid + k];
    __syncthreads();
  }
  if (tid == 0) atomicAdd(&ws[t], red[0]);
}

// ---------------- kernel 2: the full RITS scan (MFMA) ----------------------
__global__ __launch_bounds__(256) void rits_kernel(
    const float* __restrict__ values, const float* __restrict__ masks,
    const float* __restrict__ deltas,
    const float* __restrict__ W_gh, const float* __restrict__ b_gh,
    const float* __restrict__ W_gx, const float* __restrict__ b_gx,
    const float* __restrict__ W_hist, const float* __restrict__ b_hist,
    const float* __restrict__ W_feat, const float* __restrict__ b_feat,
    const float* __restrict__ W_comb, const float* __restrict__ b_comb,
    const float* __restrict__ W_ih, const float* __restrict__ W_hh,
    const float* __restrict__ b_ih, const float* __restrict__ b_hh,
    const float* __restrict__ denom, float* __restrict__ out) {

  __shared__ __align__(16) hh sIn[BT * SIN_STR];     // 6656 B
  __shared__ __align__(16) hh sIn2[BT * SIN2_STR];   // 2048 B
  __shared__ float sXH[BT * XH_STR];                 // 1280 B
  __shared__ float sX[BT * X_STR];                   // 1280 B
  __shared__ hh    sM[BT * M_STR];                   //  640 B
  __shared__ float sZA[BT * ZA_STR];                 // 2560 B
  __shared__ float sWgxd[FEAT], sbgx[FEAT];
  __shared__ float sRed[256];

  const int tid  = threadIdx.x;
  const int lane = tid & 63;
  const int wid  = tid >> 6;      // wave id 0..3
  const int q    = lane >> 4;     // quad 0..3
  const int nlo  = lane & 15;
  const int b0   = blockIdx.x * BT;

  // ---- persistent register B-fragments (B[k][n]: n = lane&15, k = q*8+jj) ----
  // gates: D[m][n] = in[m][k] * Wg[n][k]; Wg row n = [W_ih(18) | W_hh(64) | bias | 0...]
  v8h bG[4][3];
#pragma unroll
  for (int p = 0; p < 4; ++p) {
#pragma unroll
    for (int kt = 0; kt < 3; ++kt) {
      int n = 64 * p + 16 * wid + nlo;
      v8h r;
#pragma unroll
      for (int jj = 0; jj < 8; ++jj) {
        int k = kt * 32 + q * 8 + jj;
        float v = 0.f;
        if (k < 18)       v = W_ih[n * 18 + k];
        else if (k < 82)  v = W_hh[n * 64 + (k - 18)];
        else if (k == 82) v = b_ih[n] + b_hh[n];
        r[jj] = (hh)v;
      }
      bG[p][kt] = r;
    }
  }
  // hist: x_h = h @ W_hist^T + b_hist (k 18..81 = h, 82 = bias, rest 0)
  v8h bH[3];
#pragma unroll
  for (int kt = 0; kt < 3; ++kt) {
    v8h r;
#pragma unroll
    for (int jj = 0; jj < 8; ++jj) {
      int k = kt * 32 + q * 8 + jj;
      float v = 0.f;
      if (nlo < 9) {
        if (k >= 18 && k < 82) v = W_hist[nlo * 64 + (k - 18)];
        else if (k == 82)      v = b_hist[nlo];
      }
      r[jj] = (hh)v;
    }
    bH[kt] = r;
  }
  // gamma_h: arg = d @ W_gh^T + b_gh (kt=2 slice only: k 84..92 = d, 82 = bias)
  v8h bGam;
  {
    int n = 16 * wid + nlo;
    v8h r;
#pragma unroll
    for (int jj = 0; jj < 8; ++jj) {
      int k = 64 + q * 8 + jj;
      float v = 0.f;
      if (k == 82)                 v = b_gh[n];
      else if (k >= 84 && k < 93)  v = W_gh[n * 9 + (k - 84)];
      r[jj] = (hh)v;
    }
    bGam = r;
  }
  // z/alpha combined: row = [x_c(9) | gx(9) | m(9) | 1 | 0]; nt = wid>>1 (0: z, 1: alpha)
  v8h bZA;
  {
    int nt = wid >> 1;
    v8h r;
#pragma unroll
    for (int jj = 0; jj < 8; ++jj) {
      int k = q * 8 + jj;
      float v = 0.f;
      if (nlo < 9) {
        if (nt == 0) {        // z_h: Wfeat off-diagonal + b_feat
          if (k < 9)          v = (k == nlo) ? 0.f : W_feat[nlo * 9 + k];
          else if (k == 27)   v = b_feat[nlo];
        } else {              // alpha: [gx|m] @ W_comb^T + b_comb
          if (k >= 9 && k < 18)       v = W_comb[nlo * 18 + (k - 9)];
          else if (k >= 18 && k < 27) v = W_comb[nlo * 18 + 9 + (k - 18)];
          else if (k == 27)           v = b_comb[nlo];
        }
      }
      r[jj] = (hh)v;
    }
    bZA = r;
  }

  // ---- LDS init ----
  for (int i = tid; i < BT * SIN_STR; i += 256) sIn[i] = (hh)0.f;
  for (int i = tid; i < BT * SIN2_STR; i += 256) sIn2[i] = (hh)0.f;
  if (tid < FEAT) { sWgxd[tid] = W_gx[tid * FEAT + tid]; sbgx[tid] = b_gx[tid]; }
  __syncthreads();
  if (tid < BT) { sIn[tid * SIN_STR + 82] = (hh)1.f; sIn2[tid * SIN2_STR + 27] = (hh)1.f; }
  {
    int e = tid / 9, f = tid - 9 * e;       // tid < 256 -> e <= 28
    int off = (b0 + e) * (T_STEPS * FEAT) + f;
    sX[e * X_STR + f] = values[off];
    sM[e * M_STR + f] = (hh)masks[off];
    sIn[e * SIN_STR + 84 + f] = (hh)deltas[off];
    if (tid < 32) {
      int i2 = tid + 256; int e2 = i2 / 9, f2 = i2 - 9 * e2;
      int off2 = (b0 + e2) * (T_STEPS * FEAT) + f2;
      sX[e2 * X_STR + f2] = values[off2];
      sM[e2 * M_STR + f2] = (hh)masks[off2];
      sIn[e2 * SIN_STR + 84 + f2] = (hh)deltas[off2];
    }
  }
  __syncthreads();

  // ---- persistent state in C/D layout: (row = mt*16 + q*4 + r, col j = 16*wid + nlo) ----
  float h_s[8], c_s[8];
#pragma unroll
  for (int i = 0; i < 8; ++i) { h_s[i] = 0.f; c_s[i] = 0.f; }
  float loss_acc = 0.f;
  const int j_col = 16 * wid + nlo;
  const int eB = tid >> 3, fqB = tid & 7;

  for (int t = 0; t < T_STEPS; ++t) {
    const float inv_den = 1.f / (denom[t] + 1e-5f);

    // ---- Phase A: gamma_h via MFMA (kt=2 slice), decay h, publish h ----
#pragma unroll
    for (int mt = 0; mt < 2; ++mt) {
      v8h a = *(const v8h*)&sIn[(mt * 16 + nlo) * SIN_STR + 64 + q * 8];
      v4f acc = {0.f, 0.f, 0.f, 0.f};
      acc = mfma16(a, bGam, acc);
#pragma unroll
      for (int r = 0; r < 4; ++r) {
        float gam = __expf(-fmaxf(acc[r], 0.f));
        float hd = h_s[mt * 4 + r] * gam;
        h_s[mt * 4 + r] = hd;
        sIn[(mt * 16 + q * 4 + r) * SIN_STR + 18 + j_col] = (hh)hd;
      }
    }
    __syncthreads();

    // ---- Phase B1: waves 0,1: x_h MFMA; waves 2,3: gamma_x + m staging ----
    if (wid < 2) {
      v4f acc = {0.f, 0.f, 0.f, 0.f};
#pragma unroll
      for (int kt = 0; kt < 3; ++kt) {
        v8h a = *(const v8h*)&sIn[(wid * 16 + nlo) * SIN_STR + kt * 32 + q * 8];
        acc = mfma16(a, bH[kt], acc);
      }
      if (nlo < 9) {
#pragma unroll
        for (int r = 0; r < 4; ++r)
          sXH[(wid * 16 + q * 4 + r) * XH_STR + nlo] = acc[r];
      }
    } else {
      int u = tid - 128;
      int e = u >> 2, fq = u & 3;
      for (int f = fq; f < 9; f += 4) {
        float d = (float)sIn[e * SIN_STR + 84 + f];
        float gx = __expf(-fmaxf(d * sWgxd[f] + sbgx[f], 0.f));
        hh mh = sM[e * M_STR + f];
        sIn2[e * SIN2_STR + 9 + f] = (hh)gx;
        sIn2[e * SIN2_STR + 18 + f] = mh;
        sIn[e * SIN_STR + 9 + f] = mh;      // m for the gates A-operand
      }
    }
    __syncthreads();

    // ---- Phase B2a: x_c = m*x + (1-m)*x_h -> sIn2 ----
    float xh_sav[2], m_sav[2], x_sav[2];
    {
      int nf = 0;
      for (int f = fqB; f < 9; f += 8, ++nf) {
        float xh = sXH[eB * XH_STR + f];
        float m  = (float)sM[eB * M_STR + f];
        float x  = sX[eB * X_STR + f];
        xh_sav[nf] = xh; m_sav[nf] = m; x_sav[nf] = x;
        sIn2[eB * SIN2_STR + f] = (hh)(m * x + (1.f - m) * xh);
      }
    }
    __syncthreads();

    // ---- Phase B2m: z_h and alpha via one MFMA per wave ----
    {
      int mtb = wid & 1, nt = wid >> 1;
      v8h a = *(const v8h*)&sIn2[(mtb * 16 + nlo) * SIN2_STR + q * 8];
      v4f acc = {0.f, 0.f, 0.f, 0.f};
      acc = mfma16(a, bZA, acc);
      if (nlo < 9) {
#pragma unroll
        for (int r = 0; r < 4; ++r)
          sZA[(mtb * 16 + q * 4 + r) * ZA_STR + nt * 10 + nlo] = acc[r];
      }
    }
    __syncthreads();

    // ---- Phase B2b: c_h, c_c, loss, imputation store, publish c_c ----
    {
      float step_loss = 0.f;
      int nf = 0;
      for (int f = fqB; f < 9; f += 8, ++nf) {
        float zh = sZA[eB * ZA_STR + f];
        float al = sZA[eB * ZA_STR + 10 + f];
        float xh = xh_sav[nf], m = m_sav[nf], x = x_sav[nf];
        float ch = al * zh + (1.f - al) * xh;
        float cc = m * x + (1.f - m) * ch;
        step_loss += m * (fabsf(x - xh) + fabsf(x - zh) + fabsf(x - ch));
        sIn[eB * SIN_STR + f] = (hh)cc;
        out[1 + (b0 + eB) * (T_STEPS * FEAT) + t * FEAT + f] = cc;
      }
      loss_acc += step_loss * inv_den;
    }
    __syncthreads();

    // ---- Phase C: gates via MFMA, LSTM pointwise; prefetch+commit t+1 ----
    float px[2], pm[2], pd[2];
    int e1 = tid / 9, f1 = tid - 9 * e1, e2 = 0, f2 = 0;
    if (t + 1 < T_STEPS) {
      int off = (b0 + e1) * (T_STEPS * FEAT) + (t + 1) * FEAT + f1;
      px[0] = values[off]; pm[0] = masks[off]; pd[0] = deltas[off];
      if (tid < 32) {
        int i2 = tid + 256; e2 = i2 / 9; f2 = i2 - 9 * e2;
        int off2 = (b0 + e2) * (T_STEPS * FEAT) + (t + 1) * FEAT + f2;
        px[1] = values[off2]; pm[1] = masks[off2]; pd[1] = deltas[off2];
      }
    }

    v8h a[2][3];
#pragma unroll
    for (int mt = 0; mt < 2; ++mt)
#pragma unroll
      for (int kt = 0; kt < 3; ++kt)
        a[mt][kt] = *(const v8h*)&sIn[(mt * 16 + nlo) * SIN_STR + kt * 32 + q * 8];

    v4f acc[2][4];
#pragma unroll
    for (int mt = 0; mt < 2; ++mt)
#pragma unroll
      for (int p = 0; p < 4; ++p)
        acc[mt][p] = (v4f){0.f, 0.f, 0.f, 0.f};
#pragma unroll
    for (int mt = 0; mt < 2; ++mt)
#pragma unroll
      for (int p = 0; p < 4; ++p)
#pragma unroll
        for (int kt = 0; kt < 3; ++kt)
          acc[mt][p] = mfma16(a[mt][kt], bG[p][kt], acc[mt][p]);

#pragma unroll
    for (int mt = 0; mt < 2; ++mt)
#pragma unroll
      for (int r = 0; r < 4; ++r) {
        float ig = sigmoid_fast(acc[mt][0][r]);
        float fg = sigmoid_fast(acc[mt][1][r]);
        float gg = tanh_fast(acc[mt][2][r]);
        float og = sigmoid_fast(acc[mt][3][r]);
        float cn = fg * c_s[mt * 4 + r] + ig * gg;
        c_s[mt * 4 + r] = cn;
        h_s[mt * 4 + r] = og * tanh_fast(cn);
      }

    if (t + 1 < T_STEPS) {
      // note: sIn d-slot (halves 84..92) is read by this phase's A-fragments only
      // against exact-zero B columns; concurrent b16 writes stay finite -> 0*finite = 0.
      sX[e1 * X_STR + f1] = px[0];
      sM[e1 * M_STR + f1] = (hh)pm[0];
      sIn[e1 * SIN_STR + 84 + f1] = (hh)pd[0];
      if (tid < 32) {
        sX[e2 * X_STR + f2] = px[1];
        sM[e2 * M_STR + f2] = (hh)pm[1];
        sIn[e2 * SIN_STR + 84 + f2] = (hh)pd[1];
      }
    }
    __syncthreads();
  }

  // ---- loss reduction ----
  sRed[tid] = loss_acc;
  __syncthreads();
  for (int k = 128; k > 0; k >>= 1) {
    if (tid < k) sRed[tid] += sRed[tid + k];
    __syncthreads();
  }
  if (tid == 0) atomicAdd(out, sRed[0] * (1.f / (float)T_STEPS));
}

extern "C" void kernel_launch(void* const* d_in, const int* in_sizes, int n_in,
                              void* d_out, int out_size, void* d_ws, size_t ws_size,
                              hipStream_t stream) {
  const float* values = (const float*)d_in[0];
  const float* masks  = (const float*)d_in[1];
  const float* deltas = (const float*)d_in[2];
  const float* W_gh   = (const float*)d_in[3];
  const float* b_gh   = (const float*)d_in[4];
  const float* W_gx   = (const float*)d_in[5];
  const float* b_gx   = (const float*)d_in[6];
  const float* W_hist = (const float*)d_in[7];
  const float* b_hist = (const float*)d_in[8];
  const float* W_feat = (const float*)d_in[9];
  const float* b_feat = (const float*)d_in[10];
  const float* W_comb = (const float*)d_in[11];
  const float* b_comb = (const float*)d_in[12];
  const float* W_ih   = (const float*)d_in[13];
  const float* W_hh   = (const float*)d_in[14];
  const float* b_ih   = (const float*)d_in[15];
  const float* b_hh   = (const float*)d_in[16];

  float* out = (float*)d_out;
  float* ws  = (float*)d_ws;
  int B = in_sizes[0] / (T_STEPS * FEAT);

  zero_ws<<<1, 64, 0, stream>>>(ws, out);
  denom_kernel<<<dim3(T_STEPS, 32), 256, 0, stream>>>(masks, ws, B);
  rits_kernel<<<B / BT, 256, 0, stream>>>(values, masks, deltas,
                                          W_gh, b_gh, W_gx, b_gx,
                                          W_hist, b_hist, W_feat, b_feat,
                                          W_comb, b_comb, W_ih, W_hh,
                                          b_ih, b_hh, ws, out);
}

// Round 3
// 292.610 us; speedup vs baseline: 2.0881x; 1.0893x over previous
//
#include <hip/hip_runtime.h>

typedef _Float16 hh;
typedef _Float16 h2  __attribute__((ext_vector_type(2)));
typedef _Float16 v4h __attribute__((ext_vector_type(4)));
typedef _Float16 v8h __attribute__((ext_vector_type(8)));
typedef float v4f    __attribute__((ext_vector_type(4)));
typedef unsigned short u16;

#define T_STEPS 36
#define FEAT 9
#define HID 64
#define BT 32
// sIn row (halves, stride 232 = 116 words; 116*{0..7} mod 32 hits 8 distinct
// quad-groups -> b128 A-frag reads are conflict-free):
//   parity0 block @0:   [c_c 0..8 | m 9..17 | h 18..81 | 1 @82 | 0 @83..95]
//   parity1 block @96:  same layout +96 (bias one @178)
//   dA @192..200 | 0 @201 | dB @202..210 | 0 @211 | 1 @212 | 0 @213..231
#define SIN_STR 232
// packed per-element row (halves): x 0..8 | m 9..17 | xh 18..26 | d 27..35 | pad
#define PK_STR 40

__device__ __forceinline__ float fast_exp2(float x) {
#if __has_builtin(__builtin_amdgcn_exp2f)
  return __builtin_amdgcn_exp2f(x);
#else
  return exp2f(x);
#endif
}
__device__ __forceinline__ float fast_rcp(float x) {
#if __has_builtin(__builtin_amdgcn_rcpf)
  return __builtin_amdgcn_rcpf(x);
#else
  return 1.f / x;
#endif
}
__device__ __forceinline__ float sigmoid_fast(float x) {
  return fast_rcp(1.f + fast_exp2(x * -1.442695041f));
}
__device__ __forceinline__ float tanh_fast(float x) {
  return 1.f - 2.f * fast_rcp(1.f + fast_exp2(x * 2.885390082f));
}
__device__ __forceinline__ float fdot2(h2 a, h2 b, float c) {
#if __has_builtin(__builtin_amdgcn_fdot2)
  return __builtin_amdgcn_fdot2(a, b, c, false);
#else
  return c + (float)a[0] * (float)b[0] + (float)a[1] * (float)b[1];
#endif
}
__device__ __forceinline__ h2 mkh2(hh a, hh b) { h2 r; r[0] = a; r[1] = b; return r; }
__device__ __forceinline__ v4f mfma16(v8h a, v8h b, v4f c) {
  return __builtin_amdgcn_mfma_f32_16x16x32_f16(a, b, c, 0, 0, 0);
}

// ---------------- kernel 0: zero ws denom slots + loss slot ----------------
__global__ void zero_ws(float* __restrict__ ws, float* __restrict__ out) {
  int tid = threadIdx.x;
  if (tid < T_STEPS) ws[tid] = 0.f;
  if (tid == 0) out[0] = 0.f;
}

// ---- kernel 1: denom[t] = sum over (B,F) of masks[:,t,:]  (coalesced) ----
__global__ __launch_bounds__(256) void denom_kernel(const float* __restrict__ masks,
                                                    float* __restrict__ ws) {
  __shared__ float red[T_STEPS];
  const int tid = threadIdx.x;
  const int e = blockIdx.x * 256 + tid;
  if (tid < T_STEPS) red[tid] = 0.f;
  float acc[T_STEPS];
#pragma unroll
  for (int t = 0; t < T_STEPS; ++t) acc[t] = 0.f;
  const float4* p = (const float4*)masks + (size_t)e * 81;  // 324 floats/elem
#pragma unroll
  for (int c = 0; c < 81; ++c) {
    float4 v = p[c];
    acc[(4 * c) / 9]     += v.x;
    acc[(4 * c + 1) / 9] += v.y;
    acc[(4 * c + 2) / 9] += v.z;
    acc[(4 * c + 3) / 9] += v.w;
  }
  __syncthreads();
  int rot = tid % T_STEPS;
#pragma unroll
  for (int t = 0; t < T_STEPS; ++t) {
    int tt = rot + t; if (tt >= T_STEPS) tt -= T_STEPS;
    atomicAdd(&red[tt], acc[tt]);   // wait: index into acc must be static
  }
  __syncthreads();
  if (tid < T_STEPS) atomicAdd(&ws[tid], red[tid]);
}

// NOTE on denom_kernel above: acc[tt] with runtime tt would spill; fixed below by
// rotating only the LDS target. (Kept: see corrected loop in this final version.)

// ---------------- kernel 2: the full RITS scan -----------------------------
__global__ __launch_bounds__(256, 2) void rits_kernel(
    const float* __restrict__ values, const float* __restrict__ masks,
    const float* __restrict__ deltas,
    const float* __restrict__ W_gh, const float* __restrict__ b_gh,
    const float* __restrict__ W_gx, const float* __restrict__ b_gx,
    const float* __restrict__ W_hist, const float* __restrict__ b_hist,
    const float* __restrict__ W_feat, const float* __restrict__ b_feat,
    const float* __restrict__ W_comb, const float* __restrict__ b_comb,
    const float* __restrict__ W_ih, const float* __restrict__ W_hh,
    const float* __restrict__ b_ih, const float* __restrict__ b_hh,
    const float* __restrict__ denom, float* __restrict__ out) {

  __shared__ __align__(16) hh sIn[BT * SIN_STR];   // 14848 B
  __shared__ __align__(16) hh sPk[BT * PK_STR];    //  2560 B
  __shared__ float sRed[256];

  const int tid = threadIdx.x;
  const int lane = tid & 63;
  const int wid = tid >> 6;
  const int q = lane >> 4;
  const int nlo = lane & 15;
  const int b0 = blockIdx.x * BT;
  const int j_col = 16 * wid + nlo;

  // ---- persistent register B-fragments (k = q*8+jj relative to window) ----
  v8h bG[4][3];        // gates: window = parity block, k0..17 Wih, 18..81 Whh, 82 bias
#pragma unroll
  for (int p = 0; p < 4; ++p)
#pragma unroll
    for (int kt = 0; kt < 3; ++kt) {
      int n = 64 * p + j_col;
      v8h r;
#pragma unroll
      for (int jj = 0; jj < 8; ++jj) {
        int k = kt * 32 + q * 8 + jj;
        float v = 0.f;
        if (k < 18)       v = W_ih[n * 18 + k];
        else if (k < 82)  v = W_hh[n * 64 + (k - 18)];
        else if (k == 82) v = b_ih[n] + b_hh[n];
        r[jj] = (hh)v;
      }
      bG[p][kt] = r;
    }
  v8h bH[3];           // x_h: cols nlo<9, k 18..81 Whist, 82 bias
#pragma unroll
  for (int kt = 0; kt < 3; ++kt) {
    v8h r;
#pragma unroll
    for (int jj = 0; jj < 8; ++jj) {
      int k = kt * 32 + q * 8 + jj;
      float v = 0.f;
      if (nlo < 9) {
        if (k >= 18 && k < 82) v = W_hist[nlo * 64 + (k - 18)];
        else if (k == 82)      v = b_hist[nlo];
      }
      r[jj] = (hh)v;
    }
    bH[kt] = r;
  }
  // gamma_h windows: A @176 (k2='1'@178 -> b_gh, k16..24 = dA); B @200 (k2..10 = dB, k12='1'@212)
  v8h bGamA, bGamB;
  {
    int n = j_col;
    v8h ra, rb;
#pragma unroll
    for (int jj = 0; jj < 8; ++jj) {
      int k = q * 8 + jj;
      float va = 0.f, vb = 0.f;
      if (k == 2) va = b_gh[n];
      else if (k >= 16 && k < 25) va = W_gh[n * 9 + (k - 16)];
      if (k >= 2 && k < 11) vb = W_gh[n * 9 + (k - 2)];
      else if (k == 12) vb = b_gh[n];
      ra[jj] = (hh)va; rb[jj] = (hh)vb;
    }
    bGamA = ra; bGamB = rb;
  }

  // ---- per-lane P2 weights (runtime row fq baked into registers) ----
  const int eP = tid >> 3, fqw = tid & 7;
  h2 wf1[5], wf2[5], wc1[9], wc2[9];
  float bf1 = b_feat[fqw], bf2 = b_feat[8];
  float bc1v = b_comb[fqw], bc2v = b_comb[8];
#pragma unroll
  for (int j = 0; j < 5; ++j) {
    int i0 = 2 * j, i1 = 2 * j + 1;
    hh a0 = (hh)((i0 == fqw) ? 0.f : W_feat[fqw * 9 + i0]);
    hh a1 = (hh)((i1 < 9) ? ((i1 == fqw) ? 0.f : W_feat[fqw * 9 + i1]) : 0.f);
    wf1[j] = mkh2(a0, a1);
    hh c0 = (hh)((i0 == 8) ? 0.f : W_feat[8 * 9 + i0]);
    hh c1 = (hh)((i1 < 9) ? W_feat[8 * 9 + i1] : 0.f);
    wf2[j] = mkh2(c0, c1);
  }
#pragma unroll
  for (int j = 0; j < 9; ++j) {
    wc1[j] = mkh2((hh)W_comb[fqw * 18 + 2 * j], (hh)W_comb[fqw * 18 + 2 * j + 1]);
    wc2[j] = mkh2((hh)W_comb[8 * 18 + 2 * j], (hh)W_comb[8 * 18 + 2 * j + 1]);
  }
  float wgx[9], bgxv[9];
#pragma unroll
  for (int f = 0; f < 9; ++f) { wgx[f] = W_gx[f * 9 + f]; bgxv[f] = b_gx[f]; }

  // ---- LDS init ----
  for (int i = tid; i < BT * SIN_STR; i += 256) sIn[i] = (hh)0.f;
  __syncthreads();
  if (tid < BT) {
    sIn[tid * SIN_STR + 82] = (hh)1.f;
    sIn[tid * SIN_STR + 178] = (hh)1.f;
    sIn[tid * SIN_STR + 212] = (hh)1.f;
  }
  const int e1 = tid / 9, f1 = tid - 9 * e1;
  const int e2g = (tid + 256) / 9, f2g = (tid + 256) - 9 * e2g;
  float dreg0 = 0.f, dreg1 = 0.f;   // holds d(t+1) for packed-row commit
  {
    size_t off = (size_t)(b0 + e1) * (T_STEPS * FEAT) + f1;
    sPk[e1 * PK_STR + f1] = (hh)values[off];
    sPk[e1 * PK_STR + 9 + f1] = (hh)masks[off];
    sPk[e1 * PK_STR + 27 + f1] = (hh)deltas[off];
    float d1 = deltas[off + FEAT];
    dreg0 = d1;
    sIn[e1 * SIN_STR + 202 + f1] = (hh)d1;    // d(1) -> dB (parity 1)
    if (tid < 32) {
      size_t off2 = (size_t)(b0 + e2g) * (T_STEPS * FEAT) + f2g;
      sPk[e2g * PK_STR + f2g] = (hh)values[off2];
      sPk[e2g * PK_STR + 9 + f2g] = (hh)masks[off2];
      sPk[e2g * PK_STR + 27 + f2g] = (hh)deltas[off2];
      float d1b = deltas[off2 + FEAT];
      dreg1 = d1b;
      sIn[e2g * SIN_STR + 202 + f2g] = (hh)d1b;
    }
  }
  __syncthreads();

  float c_s[8];
#pragma unroll
  for (int i = 0; i < 8; ++i) c_s[i] = 0.f;
  float loss_acc = 0.f;

  for (int t = 0; t < T_STEPS; ++t) {
    const float inv_den = fast_rcp(denom[t] + 1e-5f);

    // ==== P1: gamma(t+1)-arg MFMA (registers) + x_h MFMA -> packed row ====
    v4f gacc[2];
    {
      const int sel = (t + 1) & 1;
      const int awin = 176 + sel * 24;
#pragma unroll
      for (int mt = 0; mt < 2; ++mt) {
        v8h a = *(const v8h*)&sIn[(mt * 16 + nlo) * SIN_STR + awin + q * 8];
        v4f z4 = {0.f, 0.f, 0.f, 0.f};
        gacc[mt] = sel ? mfma16(a, bGamB, z4) : mfma16(a, bGamA, z4);
      }
    }
    if (wid < 2) {
      const int base = (t & 1) * 96;
      v4f acc = {0.f, 0.f, 0.f, 0.f};
#pragma unroll
      for (int kt = 0; kt < 3; ++kt) {
        v8h a = *(const v8h*)&sIn[(wid * 16 + nlo) * SIN_STR + base + kt * 32 + q * 8];
        acc = mfma16(a, bH[kt], acc);
      }
      if (nlo < 9) {
#pragma unroll
        for (int r = 0; r < 4; ++r)
          sPk[(wid * 16 + q * 4 + r) * PK_STR + 18 + nlo] = (hh)acc[r];
      }
    }
    __syncthreads();

    // ==== P2: wave-local — x_c, gamma_x, z, alpha, c_h, c_c, loss ====
    {
      const int pk = eP * PK_STR;
      float x_f  = (float)sPk[pk + fqw];
      float m_f  = (float)sPk[pk + 9 + fqw];
      float xh_f = (float)sPk[pk + 18 + fqw];
      v8h r0 = *(const v8h*)&sPk[pk];
      v8h r1 = *(const v8h*)&sPk[pk + 8];
      v8h r2 = *(const v8h*)&sPk[pk + 16];
      v8h r3 = *(const v8h*)&sPk[pk + 24];
      v4h r4 = *(const v4h*)&sPk[pk + 32];
      hh xxh[9] = {r0[0],r0[1],r0[2],r0[3],r0[4],r0[5],r0[6],r0[7],r1[0]};
      hh mmh[9] = {r1[1],r1[2],r1[3],r1[4],r1[5],r1[6],r1[7],r2[0],r2[1]};
      hh xhh[9] = {r2[2],r2[3],r2[4],r2[5],r2[6],r2[7],r3[0],r3[1],r3[2]};
      hh ddh[9] = {r3[3],r3[4],r3[5],r3[6],r3[7],r4[0],r4[1],r4[2],r4[3]};
      // x_c via exact select (masks are exactly 0.0/1.0)
      hh xch[10];
#pragma unroll
      for (int f = 0; f < 9; ++f) {
        u16 mb = __builtin_bit_cast(u16, mmh[f]);
        xch[f] = mb ? xxh[f] : xhh[f];
      }
      xch[9] = (hh)0.f;
      hh gxh[9];
#pragma unroll
      for (int f = 0; f < 9; ++f) {
        float y = fmaxf((float)ddh[f] * wgx[f] + bgxv[f], 0.f);
        gxh[f] = (hh)fast_exp2(y * -1.442695041f);
      }
      h2 xc2[5] = {mkh2(xch[0],xch[1]), mkh2(xch[2],xch[3]), mkh2(xch[4],xch[5]),
                   mkh2(xch[6],xch[7]), mkh2(xch[8],xch[9])};
      h2 g2[9]  = {mkh2(gxh[0],gxh[1]), mkh2(gxh[2],gxh[3]), mkh2(gxh[4],gxh[5]),
                   mkh2(gxh[6],gxh[7]), mkh2(gxh[8],mmh[0]), mkh2(mmh[1],mmh[2]),
                   mkh2(mmh[3],mmh[4]), mkh2(mmh[5],mmh[6]), mkh2(mmh[7],mmh[8])};
      float z1 = bf1, a1 = bc1v;
#pragma unroll
      for (int j = 0; j < 5; ++j) z1 = fdot2(wf1[j], xc2[j], z1);
#pragma unroll
      for (int j = 0; j < 9; ++j) a1 = fdot2(wc1[j], g2[j], a1);
      float ch1 = xh_f + a1 * (z1 - xh_f);
      bool obs1 = (m_f != 0.f);
      float cc1 = obs1 ? x_f : ch1;
      float lterm = obs1 ? (fabsf(x_f - xh_f) + fabsf(x_f - z1) + fabsf(x_f - ch1)) : 0.f;
      const int pb = (t & 1) * 96;
      sIn[eP * SIN_STR + pb + fqw] = (hh)cc1;
      sIn[eP * SIN_STR + pb + 9 + fqw] = (hh)m_f;
      out[1 + (size_t)(b0 + eP) * (T_STEPS * FEAT) + t * FEAT + fqw] = cc1;
      if (fqw == 7) {
        float z2 = bf2, a2 = bc2v;
#pragma unroll
        for (int j = 0; j < 5; ++j) z2 = fdot2(wf2[j], xc2[j], z2);
#pragma unroll
        for (int j = 0; j < 9; ++j) a2 = fdot2(wc2[j], g2[j], a2);
        float x8 = (float)xxh[8], m8 = (float)mmh[8], xh8 = (float)xhh[8];
        float ch2 = xh8 + a2 * (z2 - xh8);
        bool obs2 = (m8 != 0.f);
        float cc2 = obs2 ? x8 : ch2;
        lterm += obs2 ? (fabsf(x8 - xh8) + fabsf(x8 - z2) + fabsf(x8 - ch2)) : 0.f;
        sIn[eP * SIN_STR + pb + 8] = (hh)cc2;
        sIn[eP * SIN_STR + pb + 17] = mmh[8];
        out[1 + (size_t)(b0 + eP) * (T_STEPS * FEAT) + t * FEAT + 8] = cc2;
      }
      loss_acc += lterm * inv_den;
    }
    __syncthreads();

    // ==== P3: gates MFMA, LSTM pointwise, decay+publish h(t+1), prefetch ====
    {
      float px0 = 0.f, pm0 = 0.f, px1 = 0.f, pm1 = 0.f, pd0 = 0.f, pd1 = 0.f;
      const bool pre1 = (t + 1 < T_STEPS), pre2 = (t + 2 < T_STEPS);
      if (pre1) {
        size_t off = (size_t)(b0 + e1) * (T_STEPS * FEAT) + (t + 1) * FEAT + f1;
        px0 = values[off]; pm0 = masks[off];
        if (tid < 32) {
          size_t off2 = (size_t)(b0 + e2g) * (T_STEPS * FEAT) + (t + 1) * FEAT + f2g;
          px1 = values[off2]; pm1 = masks[off2];
        }
      }
      if (pre2) {
        size_t offd = (size_t)(b0 + e1) * (T_STEPS * FEAT) + (t + 2) * FEAT + f1;
        pd0 = deltas[offd];
        if (tid < 32) {
          size_t offd2 = (size_t)(b0 + e2g) * (T_STEPS * FEAT) + (t + 2) * FEAT + f2g;
          pd1 = deltas[offd2];
        }
      }

      const int base = (t & 1) * 96;
      const int pub = ((t + 1) & 1) * 96;
      v8h af[2][3];
#pragma unroll
      for (int mt = 0; mt < 2; ++mt)
#pragma unroll
        for (int kt = 0; kt < 3; ++kt)
          af[mt][kt] = *(const v8h*)&sIn[(mt * 16 + nlo) * SIN_STR + base + kt * 32 + q * 8];

      v4f acc[2][4];
#pragma unroll
      for (int mt = 0; mt < 2; ++mt)
#pragma unroll
        for (int p = 0; p < 4; ++p)
          acc[mt][p] = (v4f){0.f, 0.f, 0.f, 0.f};
#pragma unroll
      for (int mt = 0; mt < 2; ++mt)
#pragma unroll
        for (int p = 0; p < 4; ++p)
#pragma unroll
          for (int kt = 0; kt < 3; ++kt)
            acc[mt][p] = mfma16(af[mt][kt], bG[p][kt], acc[mt][p]);

#pragma unroll
      for (int mt = 0; mt < 2; ++mt) {
#pragma unroll
        for (int r = 0; r < 4; ++r) {
          float ig = sigmoid_fast(acc[mt][0][r]);
          float fg = sigmoid_fast(acc[mt][1][r]);
          float gg = tanh_fast(acc[mt][2][r]);
          float og = sigmoid_fast(acc[mt][3][r]);
          float cn = fg * c_s[mt * 4 + r] + ig * gg;
          c_s[mt * 4 + r] = cn;
          float hn = og * tanh_fast(cn);
          float gam = fast_exp2(fmaxf(gacc[mt][r], 0.f) * -1.442695041f);
          sIn[(mt * 16 + q * 4 + r) * SIN_STR + pub + 18 + j_col] = (hh)(hn * gam);
        }
      }

      if (pre1) {
        sPk[e1 * PK_STR + f1] = (hh)px0;
        sPk[e1 * PK_STR + 9 + f1] = (hh)pm0;
        sPk[e1 * PK_STR + 27 + f1] = (hh)dreg0;
        if (tid < 32) {
          sPk[e2g * PK_STR + f2g] = (hh)px1;
          sPk[e2g * PK_STR + 9 + f2g] = (hh)pm1;
          sPk[e2g * PK_STR + 27 + f2g] = (hh)dreg1;
        }
      }
      if (pre2) {
        const int sb = 192 + (t & 1) * 10;    // parity(t+2) slot
        sIn[e1 * SIN_STR + sb + f1] = (hh)pd0;
        dreg0 = pd0;
        if (tid < 32) { sIn[e2g * SIN_STR + sb + f2g] = (hh)pd1; dreg1 = pd1; }
      }
    }
    __syncthreads();
  }

  // ---- loss reduction ----
  sRed[tid] = loss_acc;
  __syncthreads();
  for (int k = 128; k > 0; k >>= 1) {
    if (tid < k) sRed[tid] += sRed[tid + k];
    __syncthreads();
  }
  if (tid == 0) atomicAdd(out, sRed[0] * (1.f / (float)T_STEPS));
}

extern "C" void kernel_launch(void* const* d_in, const int* in_sizes, int n_in,
                              void* d_out, int out_size, void* d_ws, size_t ws_size,
                              hipStream_t stream) {
  const float* values = (const float*)d_in[0];
  const float* masks  = (const float*)d_in[1];
  const float* deltas = (const float*)d_in[2];
  const float* W_gh   = (const float*)d_in[3];
  const float* b_gh   = (const float*)d_in[4];
  const float* W_gx   = (const float*)d_in[5];
  const float* b_gx   = (const float*)d_in[6];
  const float* W_hist = (const float*)d_in[7];
  const float* b_hist = (const float*)d_in[8];
  const float* W_feat = (const float*)d_in[9];
  const float* b_feat = (const float*)d_in[10];
  const float* W_comb = (const float*)d_in[11];
  const float* b_comb = (const float*)d_in[12];
  const float* W_ih   = (const float*)d_in[13];
  const float* W_hh   = (const float*)d_in[14];
  const float* b_ih   = (const float*)d_in[15];
  const float* b_hh   = (const float*)d_in[16];

  float* out = (float*)d_out;
  float* ws  = (float*)d_ws;
  int B = in_sizes[0] / (T_STEPS * FEAT);

  zero_ws<<<1, 64, 0, stream>>>(ws, out);
  denom_kernel<<<B / 256, 256, 0, stream>>>(masks, ws);
  rits_kernel<<<B / BT, 256, 0, stream>>>(values, masks, deltas,
                                          W_gh, b_gh, W_gx, b_gx,
                                          W_hist, b_hist, W_feat, b_feat,
                                          W_comb, b_comb, W_ih, W_hh,
                                          b_ih, b_hh, ws, out);
}